// Round 1
// baseline (2424.626 us; speedup 1.0000x reference)
//
#include <hip/hip_runtime.h>
#include <stdint.h>

// ---------------- types / helpers ----------------
typedef unsigned short u16;
typedef __bf16 bf16x8 __attribute__((ext_vector_type(8)));
typedef float  f32x4  __attribute__((ext_vector_type(4)));
typedef u16    u16x4  __attribute__((ext_vector_type(4)));
typedef u16    u16x8  __attribute__((ext_vector_type(8)));

#define DEV __device__ __forceinline__

DEV u16 f2b(float f){                      // f32 -> bf16 bits, RNE
  union { float f; uint32_t u; } c; c.f = f;
  uint32_t u = c.u;
  return (u16)((u + 0x7fffu + ((u >> 16) & 1u)) >> 16);
}
DEV float b2f(u16 b){ union { uint32_t u; float f; } c; c.u = ((uint32_t)b) << 16; return c.f; }

// async global->LDS, 16B per lane, linear dest (wave-uniform base + lane*16)
#define GL2LDS(gptr, lptr) __builtin_amdgcn_global_load_lds( \
    (__attribute__((address_space(1))) void*)(gptr), \
    (__attribute__((address_space(3))) void*)(lptr), 16, 0, 0)

constexpr int SEQ = 2048, NHD = 16, DMODEL = 2048, DCQ = 1536, DC = 512, DH = 128, DR = 64;
constexpr int BATCH = 4;
constexpr int ROWS = BATCH * SEQ;          // 8192

// ---------------- elementwise f32 -> bf16 ----------------
__global__ void f32_to_bf16_k(const float* __restrict__ in, u16* __restrict__ out, long long n){
  long long i = ((long long)blockIdx.x * 256 + threadIdx.x) * 8;
  if (i + 8 > n) return;                   // n is an exact multiple in all uses
  float4 a = *(const float4*)(in + i);
  float4 b = *(const float4*)(in + i + 4);
  u16x8 v;
  v[0]=f2b(a.x); v[1]=f2b(a.y); v[2]=f2b(a.z); v[3]=f2b(a.w);
  v[4]=f2b(b.x); v[5]=f2b(b.y); v[6]=f2b(b.z); v[7]=f2b(b.w);
  *(u16x8*)(out + i) = v;
}

// ---------------- weight transpose W[K][N] f32 -> WT[Npad][K] bf16 (pad rows zero) ----------
__global__ void transpose_w(const float* __restrict__ W, u16* __restrict__ WT,
                            int K, int N, int Npad){
  __shared__ float tile[32][33];
  int k0 = blockIdx.x * 32, n0 = blockIdx.y * 32;
  int tx = threadIdx.x, ty = threadIdx.y;
  #pragma unroll
  for (int dy = 0; dy < 32; dy += 8){
    int n = n0 + tx;
    tile[ty + dy][tx] = (n < N) ? W[(size_t)(k0 + ty + dy) * N + n] : 0.f;
  }
  __syncthreads();
  #pragma unroll
  for (int dy = 0; dy < 32; dy += 8){
    int n = n0 + ty + dy, k = k0 + tx;
    WT[(size_t)n * K + k] = f2b(tile[tx][ty + dy]);
  }
}

// ---------------- generic batched GEMM: C[m][n] = scale * sum_k A[m][k] * Bt[n][k] (+bias) ----
// A bf16 (or f32 converted in staging), Bt bf16. 128x128 tile, BK=32, 4 waves (2x2 of 64x64).
#define BM 128
#define BN 128
#define BK 32

template<bool A_F32, bool CAUSAL_SKIP, bool K_LIMIT, bool OUT_BF16, bool HAS_BIAS>
__global__ __launch_bounds__(256, 2) void gemm_bt(
    const void* __restrict__ Ap, const u16* __restrict__ Btp,
    float* __restrict__ Cf, u16* __restrict__ Cb,
    const float* __restrict__ bias,
    int K, int lda, int ldb, int ldc,
    long long sAb, long long sAh, long long sBb, long long sBh,
    long long sCb, long long sCh, int nH, float scale)
{
  const int bm = blockIdx.x, bn = blockIdx.y, z = blockIdx.z;
  if (CAUSAL_SKIP && bn > bm) return;      // tile fully above causal diagonal
  const int zb = z / nH, zh = z % nH;
  const size_t offA = (size_t)zb * sAb + (size_t)zh * sAh;
  const size_t offB = (size_t)zb * sBb + (size_t)zh * sBh;
  const size_t offC = (size_t)zb * sCb + (size_t)zh * sCh;

  int Keff = K;
  if (K_LIMIT){ int kl = (bm + 1) * BM; Keff = kl < K ? kl : K; }

  __shared__ __align__(16) u16 As[BM * BK];
  __shared__ __align__(16) u16 Bs[BN * BK];

  const int t = threadIdx.x;
  const int wid = t >> 6, lane = t & 63;
  const int wm = (wid >> 1) << 6, wn = (wid & 1) << 6;
  const int lr = lane & 15, kg = lane >> 4;

  f32x4 acc[4][4];
  #pragma unroll
  for (int i = 0; i < 4; i++)
    #pragma unroll
    for (int j = 0; j < 4; j++) acc[i][j] = (f32x4){0.f, 0.f, 0.f, 0.f};

  const u16*   Abf = (const u16*)Ap + offA;
  const float* Af  = (const float*)Ap + offA;
  const u16*   Bt  = Btp + offB;

  for (int k0 = 0; k0 < Keff; k0 += BK){
    if (!A_F32){
      #pragma unroll
      for (int jj = 0; jj < 2; jj++){
        int idx = t + jj * 256; int r = idx >> 2, cp = idx & 3;
        GL2LDS(Abf + (size_t)(bm * BM + r) * lda + k0 + cp * 8, &As[idx * 8]);
      }
    } else {
      #pragma unroll
      for (int jj = 0; jj < 2; jj++){
        int idx = t + jj * 256; int r = idx >> 2, cp = idx & 3;
        const float* src = Af + (size_t)(bm * BM + r) * lda + k0 + cp * 8;
        float4 a = *(const float4*)src;
        float4 b = *(const float4*)(src + 4);
        u16x8 v;
        v[0]=f2b(a.x); v[1]=f2b(a.y); v[2]=f2b(a.z); v[3]=f2b(a.w);
        v[4]=f2b(b.x); v[5]=f2b(b.y); v[6]=f2b(b.z); v[7]=f2b(b.w);
        *(u16x8*)&As[idx * 8] = v;
      }
    }
    #pragma unroll
    for (int jj = 0; jj < 2; jj++){
      int idx = t + jj * 256; int r = idx >> 2, cp = idx & 3;
      GL2LDS(Bt + (size_t)(bn * BN + r) * ldb + k0 + cp * 8, &Bs[idx * 8]);
    }
    __syncthreads();                        // drains vmcnt (global_load_lds) + lgkm

    bf16x8 afr[4], bfr[4];
    #pragma unroll
    for (int i = 0; i < 4; i++) afr[i] = *(const bf16x8*)&As[(wm + i * 16 + lr) * BK + kg * 8];
    #pragma unroll
    for (int j = 0; j < 4; j++) bfr[j] = *(const bf16x8*)&Bs[(wn + j * 16 + lr) * BK + kg * 8];
    #pragma unroll
    for (int i = 0; i < 4; i++)
      #pragma unroll
      for (int j = 0; j < 4; j++)
        acc[i][j] = __builtin_amdgcn_mfma_f32_16x16x32_bf16(afr[i], bfr[j], acc[i][j], 0, 0, 0);
    __syncthreads();
  }

  // epilogue: C/D mapping col = lane&15, row = (lane>>4)*4 + reg
  const int crow = bm * BM + wm, ccol = bn * BN + wn;
  #pragma unroll
  for (int j = 0; j < 4; j++){
    int c = ccol + j * 16 + lr;
    float bv = HAS_BIAS ? bias[c] : 0.f;
    #pragma unroll
    for (int i = 0; i < 4; i++){
      #pragma unroll
      for (int rg = 0; rg < 4; rg++){
        int r = crow + i * 16 + kg * 4 + rg;
        float v = acc[i][j][rg] * scale + bv;
        size_t o = offC + (size_t)r * ldc + c;
        if (OUT_BF16) Cb[o] = f2b(v); else Cf[o] = v;
      }
    }
  }
}

// ---------------- RMSNorm (f32 in, bf16 out), one row per block ----------------
__global__ __launch_bounds__(256) void rmsnorm_bf(const float* __restrict__ in,
                                                  const float* __restrict__ g,
                                                  u16* __restrict__ out, int W){
  int row = blockIdx.x;
  const float* x = in + (size_t)row * W;
  u16* op = out + (size_t)row * W;
  float ss = 0.f;
  for (int c = threadIdx.x * 4; c < W; c += 1024){
    float4 v = *(const float4*)(x + c);
    ss += v.x*v.x + v.y*v.y + v.z*v.z + v.w*v.w;
  }
  #pragma unroll
  for (int o = 32; o; o >>= 1) ss += __shfl_xor(ss, o);
  __shared__ float red[4];
  if ((threadIdx.x & 63) == 0) red[threadIdx.x >> 6] = ss;
  __syncthreads();
  float tot = red[0] + red[1] + red[2] + red[3];
  float r = rsqrtf(tot / (float)W + 1e-6f);
  for (int c = threadIdx.x * 4; c < W; c += 1024){
    float4 v  = *(const float4*)(x + c);
    float4 gv = *(const float4*)(g + c);
    u16x4 o4;
    o4[0] = f2b(v.x * r * gv.x); o4[1] = f2b(v.y * r * gv.y);
    o4[2] = f2b(v.z * r * gv.z); o4[3] = f2b(v.w * r * gv.w);
    *(u16x4*)(op + c) = o4;
  }
}

// ---------------- kR path: +bias, rmsnorm(64), rope -> f32 [8192][64] ----------------
__global__ void kr_rope(const float* __restrict__ kRpre, const float* __restrict__ bkr,
                        const float* __restrict__ gkr, const float* __restrict__ freqs,
                        float* __restrict__ kRr){
  int row = blockIdx.x, lane = threadIdx.x;
  int s = row & (SEQ - 1);
  float x = kRpre[(size_t)row * 128 + lane] + bkr[lane];
  float ss = x * x;
  #pragma unroll
  for (int o = 32; o; o >>= 1) ss += __shfl_xor(ss, o);
  float r = rsqrtf(ss * (1.0f / 64.0f) + 1e-6f);
  float xn = x * r * gkr[lane];
  float pr = __shfl_xor(xn, 1);
  int i = lane >> 1;
  float cs = freqs[((size_t)s * 32 + i) * 2 + 0];
  float sn = freqs[((size_t)s * 32 + i) * 2 + 1];
  float o2 = ((lane & 1) == 0) ? (xn * cs - pr * sn) : (pr * sn + xn * cs);
  kRr[(size_t)row * 64 + lane] = o2;
}

// ---------------- assemble q = [qC | rope(qR)] into [B][H][S][192] bf16 ----------------
__global__ void build_q(const u16* __restrict__ qC, const u16* __restrict__ qR,
                        const float* __restrict__ freqs, u16* __restrict__ qb){
  int row = blockIdx.x, hh = blockIdx.y, j = threadIdx.x;
  int b = row >> 11, s = row & (SEQ - 1);
  size_t qo = ((size_t)(b * NHD + hh) * SEQ + s) * 192;
  qb[qo + j]      = qC[(size_t)row * 2048 + hh * 128 + j];
  qb[qo + 64 + j] = qC[(size_t)row * 2048 + hh * 128 + 64 + j];
  float xr = b2f(qR[(size_t)row * 1024 + hh * 64 + j]);
  float pr = __shfl_xor(xr, 1);
  int i = j >> 1;
  float cs = freqs[((size_t)s * 32 + i) * 2 + 0];
  float sn = freqs[((size_t)s * 32 + i) * 2 + 1];
  float o = ((j & 1) == 0) ? (xr * cs - pr * sn) : (pr * sn + xr * cs);
  qb[qo + 128 + j] = f2b(o);
}

// ---------------- assemble k = [kR | kC] into [B][H][S][192] bf16 ----------------
__global__ void build_k(const float* __restrict__ kRr, const u16* __restrict__ kC,
                        u16* __restrict__ kb){
  int row = blockIdx.x, hh = blockIdx.y, j = threadIdx.x;
  int b = row >> 11, s = row & (SEQ - 1);
  size_t ko = ((size_t)(b * NHD + hh) * SEQ + s) * 192;
  kb[ko + j]       = f2b(kRr[(size_t)row * 64 + j]);
  kb[ko + 64 + j]  = kC[(size_t)row * 2048 + hh * 128 + j];
  kb[ko + 128 + j] = kC[(size_t)row * 2048 + hh * 128 + 64 + j];
}

// ---------------- v transpose: [b][s][h][d] -> [b][h][d][s] bf16 ----------------
__global__ void build_vT(const u16* __restrict__ vC, u16* __restrict__ vT){
  __shared__ u16 tile[32][33];
  int z = blockIdx.z; int b = z >> 4, hh = z & 15;
  int s0 = blockIdx.x * 32, d0 = blockIdx.y * 32;
  int tx = threadIdx.x, ty = threadIdx.y;
  #pragma unroll
  for (int dy = 0; dy < 32; dy += 8)
    tile[ty + dy][tx] = vC[((size_t)(b * SEQ + s0 + ty + dy)) * 2048 + hh * 128 + d0 + tx];
  __syncthreads();
  #pragma unroll
  for (int dy = 0; dy < 32; dy += 8)
    vT[((size_t)z * 128 + d0 + ty + dy) * SEQ + s0 + tx] = tile[tx][ty + dy];
}

// ---------------- causal softmax in place on w[b][h][q][k]; zeros masked tail ----------
__global__ __launch_bounds__(256) void softmax_causal(float* __restrict__ w){
  const int q = blockIdx.x, z = blockIdx.y;
  float* row = w + ((size_t)z * SEQ + q) * SEQ;
  const int n = q + 1, t = threadIdx.x;
  float v[8];
  float mx = -3.4e38f;
  #pragma unroll
  for (int k = 0; k < 8; k++){
    int i = t + k * 256;
    float x = (i < n) ? row[i] : -3.4e38f;
    v[k] = x; mx = fmaxf(mx, x);
  }
  #pragma unroll
  for (int o = 32; o; o >>= 1) mx = fmaxf(mx, __shfl_xor(mx, o));
  __shared__ float redm[4];
  if ((t & 63) == 0) redm[t >> 6] = mx;
  __syncthreads();
  mx = fmaxf(fmaxf(redm[0], redm[1]), fmaxf(redm[2], redm[3]));
  float s = 0.f;
  #pragma unroll
  for (int k = 0; k < 8; k++){
    int i = t + k * 256;
    float e = (i < n) ? __expf(v[k] - mx) : 0.f;
    v[k] = e; s += e;
  }
  #pragma unroll
  for (int o = 32; o; o >>= 1) s += __shfl_xor(s, o);
  __shared__ float reds[4];
  if ((t & 63) == 0) reds[t >> 6] = s;
  __syncthreads();
  s = reds[0] + reds[1] + reds[2] + reds[3];
  float rs = 1.0f / s;
  #pragma unroll
  for (int k = 0; k < 8; k++){
    int i = t + k * 256;
    row[i] = v[k] * rs;          // masked tail: v[k]==0 -> exact 0.0f
  }
}

// ---------------- launch ----------------
extern "C" void kernel_launch(void* const* d_in, const int* in_sizes, int n_in,
                              void* d_out, int out_size, void* d_ws, size_t ws_size,
                              hipStream_t stream) {
  (void)in_sizes; (void)n_in; (void)out_size; (void)ws_size;
  const float* h     = (const float*)d_in[0];
  const float* freqs = (const float*)d_in[1];
  // d_in[2] = mask (causal by construction; not needed)
  const float* Wqd  = (const float*)d_in[3];
  const float* bqd  = (const float*)d_in[4];
  const float* gq   = (const float*)d_in[5];
  const float* Wqc  = (const float*)d_in[6];
  const float* bqc  = (const float*)d_in[7];
  const float* Wqr  = (const float*)d_in[8];
  const float* bqr  = (const float*)d_in[9];
  const float* Wkr  = (const float*)d_in[10];
  const float* bkr  = (const float*)d_in[11];
  const float* gkr  = (const float*)d_in[12];
  const float* Wkvd = (const float*)d_in[13];
  const float* bkvd = (const float*)d_in[14];
  const float* gkv  = (const float*)d_in[15];
  const float* Wkc  = (const float*)d_in[16];
  const float* bkc  = (const float*)d_in[17];
  const float* Wvc  = (const float*)d_in[18];
  const float* bvc  = (const float*)d_in[19];
  const float* Wo   = (const float*)d_in[20];
  const float* bo   = (const float*)d_in[21];

  float* h_out = (float*)d_out;
  float* w_att = h_out + (size_t)BATCH * SEQ * DMODEL;   // [B][H][S][S] f32

  char* wsp = (char*)d_ws;
  size_t off = 0;
  auto alloc = [&](size_t bytes) -> void* {
    void* p = wsp + off; off += (bytes + 255) & ~(size_t)255; return p;
  };

  u16* h_bf    = (u16*)alloc((size_t)ROWS * DMODEL * 2);
  u16* WqdT    = (u16*)alloc((size_t)DCQ * DMODEL * 2);
  u16* WkvdT   = (u16*)alloc((size_t)DC * DMODEL * 2);
  u16* WkrT    = (u16*)alloc((size_t)128 * DMODEL * 2);        // padded 64->128
  u16* WqcT    = (u16*)alloc((size_t)(NHD * DH) * DCQ * 2);
  u16* WqrT    = (u16*)alloc((size_t)(NHD * DR) * DCQ * 2);
  u16* WkcT    = (u16*)alloc((size_t)(NHD * DH) * DC * 2);
  u16* WvcT    = (u16*)alloc((size_t)(NHD * DH) * DC * 2);
  u16* WoT     = (u16*)alloc((size_t)DMODEL * (NHD * DH) * 2);
  float* cQpre  = (float*)alloc((size_t)ROWS * DCQ * 4);
  float* cKVpre = (float*)alloc((size_t)ROWS * DC * 4);
  float* kRpre  = (float*)alloc((size_t)ROWS * 128 * 4);
  u16* cQbf    = (u16*)alloc((size_t)ROWS * DCQ * 2);
  u16* cKVbf   = (u16*)alloc((size_t)ROWS * DC * 2);
  float* kRr   = (float*)alloc((size_t)ROWS * DR * 4);
  u16* qCbf    = (u16*)alloc((size_t)ROWS * NHD * DH * 2);
  u16* qRbf    = (u16*)alloc((size_t)ROWS * NHD * DR * 2);
  u16* kCbf    = (u16*)alloc((size_t)ROWS * NHD * DH * 2);
  u16* vCbf    = (u16*)alloc((size_t)ROWS * NHD * DH * 2);
  u16* qbf     = (u16*)alloc((size_t)BATCH * NHD * SEQ * 192 * 2);
  u16* kbf     = (u16*)alloc((size_t)BATCH * NHD * SEQ * 192 * 2);
  u16* vTbf    = (u16*)alloc((size_t)BATCH * NHD * DH * SEQ * 2);
  u16* attnbf  = (u16*)alloc((size_t)ROWS * NHD * DH * 2);

  dim3 tb(32, 8);
  // input + weight conversion
  f32_to_bf16_k<<<8192, 256, 0, stream>>>(h, h_bf, (long long)ROWS * DMODEL);
  transpose_w<<<dim3(64, 48), tb, 0, stream>>>(Wqd,  WqdT,  2048, 1536, 1536);
  transpose_w<<<dim3(64, 16), tb, 0, stream>>>(Wkvd, WkvdT, 2048, 512,  512);
  transpose_w<<<dim3(64, 4 ), tb, 0, stream>>>(Wkr,  WkrT,  2048, 64,   128);
  transpose_w<<<dim3(48, 64), tb, 0, stream>>>(Wqc,  WqcT,  1536, 2048, 2048);
  transpose_w<<<dim3(48, 32), tb, 0, stream>>>(Wqr,  WqrT,  1536, 1024, 1024);
  transpose_w<<<dim3(16, 64), tb, 0, stream>>>(Wkc,  WkcT,  512,  2048, 2048);
  transpose_w<<<dim3(16, 64), tb, 0, stream>>>(Wvc,  WvcT,  512,  2048, 2048);
  transpose_w<<<dim3(64, 64), tb, 0, stream>>>(Wo,   WoT,   2048, 2048, 2048);

  // down projections (f32 out, bias; rmsnorm follows)
  gemm_bt<false,false,false,false,true><<<dim3(64,12,1),256,0,stream>>>(
      h_bf, WqdT, cQpre, nullptr, bqd, 2048, 2048, 2048, 1536, 0,0,0,0,0,0, 1, 1.f);
  gemm_bt<false,false,false,false,true><<<dim3(64,4,1),256,0,stream>>>(
      h_bf, WkvdT, cKVpre, nullptr, bkvd, 2048, 2048, 2048, 512, 0,0,0,0,0,0, 1, 1.f);
  gemm_bt<false,false,false,false,false><<<dim3(64,1,1),256,0,stream>>>(
      h_bf, WkrT, kRpre, nullptr, nullptr, 2048, 2048, 2048, 128, 0,0,0,0,0,0, 1, 1.f);

  rmsnorm_bf<<<ROWS, 256, 0, stream>>>(cQpre,  gq,  cQbf,  DCQ);
  rmsnorm_bf<<<ROWS, 256, 0, stream>>>(cKVpre, gkv, cKVbf, DC);
  kr_rope<<<ROWS, 64, 0, stream>>>(kRpre, bkr, gkr, freqs, kRr);

  // up projections (bf16 out + bias)
  gemm_bt<false,false,false,true,true><<<dim3(64,16,1),256,0,stream>>>(
      cQbf, WqcT, nullptr, qCbf, bqc, 1536, 1536, 1536, 2048, 0,0,0,0,0,0, 1, 1.f);
  gemm_bt<false,false,false,true,true><<<dim3(64,8,1),256,0,stream>>>(
      cQbf, WqrT, nullptr, qRbf, bqr, 1536, 1536, 1536, 1024, 0,0,0,0,0,0, 1, 1.f);
  gemm_bt<false,false,false,true,true><<<dim3(64,16,1),256,0,stream>>>(
      cKVbf, WkcT, nullptr, kCbf, bkc, 512, 512, 512, 2048, 0,0,0,0,0,0, 1, 1.f);
  gemm_bt<false,false,false,true,true><<<dim3(64,16,1),256,0,stream>>>(
      cKVbf, WvcT, nullptr, vCbf, bvc, 512, 512, 512, 2048, 0,0,0,0,0,0, 1, 1.f);

  // assemble q / k / vT
  build_q<<<dim3(ROWS, NHD), 64, 0, stream>>>(qCbf, qRbf, freqs, qbf);
  build_k<<<dim3(ROWS, NHD), 64, 0, stream>>>(kRr, kCbf, kbf);
  build_vT<<<dim3(64, 4, 64), tb, 0, stream>>>(vCbf, vTbf);

  // scores = scale * q.kT per (b,h); skip tiles above diagonal
  gemm_bt<false,true,false,false,false><<<dim3(16,16,64),256,0,stream>>>(
      qbf, kbf, w_att, nullptr, nullptr, 192, 192, 192, SEQ,
      (long long)NHD*SEQ*192, (long long)SEQ*192,
      (long long)NHD*SEQ*192, (long long)SEQ*192,
      (long long)NHD*SEQ*SEQ, (long long)SEQ*SEQ, NHD, 0.07216878364870323f);

  softmax_causal<<<dim3(SEQ, BATCH*NHD), 256, 0, stream>>>(w_att);

  // out = w @ v per (b,h), K limited by causal row tile; bf16 out into [b][q][h][d]
  gemm_bt<true,false,true,true,false><<<dim3(16,1,64),256,0,stream>>>(
      w_att, vTbf, nullptr, attnbf, nullptr, SEQ, SEQ, SEQ, NHD*DH,
      (long long)NHD*SEQ*SEQ, (long long)SEQ*SEQ,
      (long long)NHD*DH*SEQ,  (long long)DH*SEQ,
      (long long)SEQ*NHD*DH,  (long long)DH, NHD, 1.f);

  // h_out = attn @ Wo + bo
  gemm_bt<false,false,false,false,true><<<dim3(64,16,1),256,0,stream>>>(
      attnbf, WoT, h_out, nullptr, bo, 2048, 2048, 2048, 2048, 0,0,0,0,0,0, 1, 1.f);
}